// Round 9
// baseline (94.398 us; speedup 1.0000x reference)
//
#include <hip/hip_runtime.h>
#include <stdint.h>

// Two-kernel 3x3 neighborhood-attention.
//  K1 coef2_kernel: block = one image row, 128 threads (2 waves), thread = 2
//    adjacent pixels. Channels stream through double-buffered LDS via
//    global_load_lds (16B/lane). Consume uses 3 aligned ds_read_b64 per row
//    (window x0-2..x0+3) + 1 b64 ref -> half the DS-pipe issue cost of R7.
//    Chunk loop fully unrolled so buffer indices are compile-time constants
//    (prevents conservative vmcnt(0) between stage(i+1) and consume(i)).
//    Reflect x-edges via +-2-float LDS pad + cndmask. No cross-lane reduce.
//  K2 apply_kernel: float4 streaming out = exp(-(nbr-ref)^2)*sum_k coef_k*nbr_k.
// Shapes: [b=2, c=64, h=256, w=256] fp32.

constexpr int C = 64, H = 256, W = 256, HW = H * W;
constexpr int B = 2, PIX = B * HW;
constexpr int CHUNK = 8;            // channels per staged chunk
constexpr int NCHUNK = C / CHUNK;   // 8

typedef const __attribute__((address_space(1))) void* gas_ptr;
typedef __attribute__((address_space(3))) void* las_ptr;

// ---------------- K1: coefficient kernel (LDS-staged, 2px/thread) ----------------
__global__ __launch_bounds__(128) void coef2_kernel(const float* __restrict__ nbr,
                                                    const float* __restrict__ ref,
                                                    float* __restrict__ coef) {
  // flat buf: [2 dbuf][CHUNK ch][4 rows (3 nbr + 1 ref)][W], +-2-float pads
  __shared__ float bufraw[2 + 2 * CHUNK * 4 * W + 2];
  float* buff = bufraw + 2;   // 8B-aligned; index ((bi*CHUNK+cc)*4+rw)*W + x

  const int tid  = threadIdx.x;     // 0..127
  const int lane = tid & 63;
  const int wv   = tid >> 6;        // wave 0..1

  const int by = blockIdx.x;        // b*256 + y
  const int b  = by >> 8;
  const int y  = by & 255;
  const int ym = (y == 0)     ? 1     : y - 1;   // jnp reflect
  const int yp = (y == H - 1) ? H - 2 : y + 1;

  const float* nbase = nbr + (size_t)b * C * HW;
  const float* rbase = ref + (size_t)b * C * HW;
  const int rowoff0 = ym * W, rowoff1 = y * W, rowoff2 = yp * W;

  // stage chunk -> buf[bi]: wave wv stages channels 4wv..4wv+3 (16 gll each)
  auto stage = [&](int chunk, int bi) {
#pragma unroll
    for (int u = 0; u < 4; ++u) {
      const int cc = 4 * wv + u;
      const int c  = chunk * CHUNK + cc;
      const float* nrow = nbase + (size_t)c * HW;
      const float* rrow = rbase + (size_t)c * HW;
      float* lb = buff + ((bi * CHUNK + cc) * 4) * W;
      __builtin_amdgcn_global_load_lds((gas_ptr)(nrow + rowoff0 + lane * 4),
                                       (las_ptr)(lb + 0 * W), 16, 0, 0);
      __builtin_amdgcn_global_load_lds((gas_ptr)(nrow + rowoff1 + lane * 4),
                                       (las_ptr)(lb + 1 * W), 16, 0, 0);
      __builtin_amdgcn_global_load_lds((gas_ptr)(nrow + rowoff2 + lane * 4),
                                       (las_ptr)(lb + 2 * W), 16, 0, 0);
      __builtin_amdgcn_global_load_lds((gas_ptr)(rrow + rowoff1 + lane * 4),
                                       (las_ptr)(lb + 3 * W), 16, 0, 0);
    }
  };

  const int x0 = 2 * tid;           // even, 0..254; pixels {x0, x0+1}

  float sr0 = 0.f, sr1 = 0.f;
  float dot0[9], ss0[9], dot1[9], ss1[9];
#pragma unroll
  for (int k = 0; k < 9; ++k) { dot0[k] = ss0[k] = dot1[k] = ss1[k] = 0.f; }

  stage(0, 0);
  __syncthreads();   // drains vmcnt -> chunk 0 visible

#pragma unroll
  for (int i = 0; i < NCHUNK; ++i) {
    const int bi = i & 1;           // compile-time after unroll
    if (i + 1 < NCHUNK) stage(i + 1, bi ^ 1);
#pragma unroll
    for (int cc = 0; cc < CHUNK; ++cc) {
      const float* base = buff + ((bi * CHUNK + cc) * 4) * W;
      const float2 rr = *(const float2*)(base + 3 * W + x0);
      const float r0 = rr.x, r1 = rr.y;
      sr0 = fmaf(r0, r0, sr0);
      sr1 = fmaf(r1, r1, sr1);
#pragma unroll
      for (int rw = 0; rw < 3; ++rw) {
        const float* rp = base + rw * W;
        const float2 q0 = *(const float2*)(rp + x0 - 2);   // pad-safe at x0=0
        const float2 q1 = *(const float2*)(rp + x0);
        const float2 q2 = *(const float2*)(rp + x0 + 2);   // pad-safe at x0=254
        // reflect: px0 left at x0=0 -> idx 1 (=q1.y); px1 right at x0=254 -> idx 254 (=q1.x)
        const float m0 = (x0 == 0)     ? q1.y : q0.y;
        const float m1 = (x0 == W - 2) ? q1.x : q2.x;
        const int k = rw * 3;
        dot0[k + 0] = fmaf(r0, m0,   dot0[k + 0]); ss0[k + 0] = fmaf(m0,   m0,   ss0[k + 0]);
        dot0[k + 1] = fmaf(r0, q1.x, dot0[k + 1]); ss0[k + 1] = fmaf(q1.x, q1.x, ss0[k + 1]);
        dot0[k + 2] = fmaf(r0, q1.y, dot0[k + 2]); ss0[k + 2] = fmaf(q1.y, q1.y, ss0[k + 2]);
        dot1[k + 0] = fmaf(r1, q1.x, dot1[k + 0]); ss1[k + 0] = fmaf(q1.x, q1.x, ss1[k + 0]);
        dot1[k + 1] = fmaf(r1, q1.y, dot1[k + 1]); ss1[k + 1] = fmaf(q1.y, q1.y, ss1[k + 1]);
        dot1[k + 2] = fmaf(r1, m1,   dot1[k + 2]); ss1[k + 2] = fmaf(m1,   m1,   ss1[k + 2]);
      }
    }
    __syncthreads();   // next chunk ready + protects dbuf reuse
  }

  // ---- normalize + softmax for both pixels ----
  const float invr0 = __frsqrt_rn(fmaxf(sr0, 1e-24f));
  const float invr1 = __frsqrt_rn(fmaxf(sr1, 1e-24f));
  float d0[9], d1[9], ip0[9], ip1[9];
  float mx0 = -INFINITY, mx1 = -INFINITY;
#pragma unroll
  for (int k = 0; k < 9; ++k) {
    ip0[k] = __frsqrt_rn(fmaxf(ss0[k], 1e-24f));
    ip1[k] = __frsqrt_rn(fmaxf(ss1[k], 1e-24f));
    d0[k]  = dot0[k] * invr0 * ip0[k];
    d1[k]  = dot1[k] * invr1 * ip1[k];
    mx0 = fmaxf(mx0, d0[k]);
    mx1 = fmaxf(mx1, d1[k]);
  }
  float s0 = 0.f, s1 = 0.f;
  float c0[9], c1[9];
#pragma unroll
  for (int k = 0; k < 9; ++k) {
    c0[k] = __expf(d0[k] - mx0); s0 += c0[k];
    c1[k] = __expf(d1[k] - mx1); s1 += c1[k];
  }
  const float si0 = 1.0f / s0, si1 = 1.0f / s1;

  const int pix0 = by * W + x0;      // b*HW + y*W + x0 (even)
#pragma unroll
  for (int k = 0; k < 9; ++k) {
    float2 cf;
    cf.x = c0[k] * si0 * ip0[k];     // patch l2norm folded into weight
    cf.y = c1[k] * si1 * ip1[k];
    *(float2*)(coef + (size_t)k * PIX + pix0) = cf;
  }
}

// ---------------- K2: apply kernel (proven; unchanged) ----------------
__global__ __launch_bounds__(256) void apply_kernel(const float* __restrict__ nbr,
                                                    const float* __restrict__ ref,
                                                    const float* __restrict__ coef,
                                                    float* __restrict__ out) {
  const int gid  = blockIdx.x * 256 + threadIdx.x;
  const int lane = gid & 63;
  const int x0   = lane * 4;
  const int t    = gid >> 6;
  const int y    = t & 255;
  const int u    = t >> 8;
  const int b    = u >> 5;
  const int c0   = (u & 31) * 2;

  const int ym = (y == 0)     ? 1     : y - 1;
  const int yp = (y == H - 1) ? H - 2 : y + 1;

  const float* n0  = nbr + ((size_t)b * C + c0) * HW;
  const float* n1  = n0 + HW;
  const float* r0p = ref + ((size_t)b * C + c0) * HW;
  float*       o0  = out + ((size_t)b * C + c0) * HW;

  const float4 a0 = *(const float4*)(n0 + ym * W + x0);
  const float4 a1 = *(const float4*)(n0 + y  * W + x0);
  const float4 a2 = *(const float4*)(n0 + yp * W + x0);
  const float4 b0 = *(const float4*)(n1 + ym * W + x0);
  const float4 b1 = *(const float4*)(n1 + y  * W + x0);
  const float4 b2 = *(const float4*)(n1 + yp * W + x0);
  const float4 f0 = *(const float4*)(r0p + y * W + x0);
  const float4 f1 = *(const float4*)(r0p + HW + y * W + x0);

  float La0 = __shfl(a0.w, lane - 1), Ra0 = __shfl(a0.x, lane + 1);
  float La1 = __shfl(a1.w, lane - 1), Ra1 = __shfl(a1.x, lane + 1);
  float La2 = __shfl(a2.w, lane - 1), Ra2 = __shfl(a2.x, lane + 1);
  float Lb0 = __shfl(b0.w, lane - 1), Rb0 = __shfl(b0.x, lane + 1);
  float Lb1 = __shfl(b1.w, lane - 1), Rb1 = __shfl(b1.x, lane + 1);
  float Lb2 = __shfl(b2.w, lane - 1), Rb2 = __shfl(b2.x, lane + 1);
  if (lane == 0)  { La0 = a0.y; La1 = a1.y; La2 = a2.y; Lb0 = b0.y; Lb1 = b1.y; Lb2 = b2.y; }
  if (lane == 63) { Ra0 = a0.z; Ra1 = a1.z; Ra2 = a2.z; Rb0 = b0.z; Rb1 = b1.z; Rb2 = b2.z; }

  float va[3][6] = {{La0, a0.x, a0.y, a0.z, a0.w, Ra0},
                    {La1, a1.x, a1.y, a1.z, a1.w, Ra1},
                    {La2, a2.x, a2.y, a2.z, a2.w, Ra2}};
  float vb[3][6] = {{Lb0, b0.x, b0.y, b0.z, b0.w, Rb0},
                    {Lb1, b1.x, b1.y, b1.z, b1.w, Rb1},
                    {Lb2, b2.x, b2.y, b2.z, b2.w, Rb2}};

  const int cbase = b * HW + y * W + x0;
  float aga[4] = {0.f, 0.f, 0.f, 0.f};
  float agb[4] = {0.f, 0.f, 0.f, 0.f};
#pragma unroll
  for (int k = 0; k < 9; ++k) {
    const float4 cf = *(const float4*)(coef + (size_t)k * PIX + cbase);
    const int r  = k / 3;
    const int cx = k % 3;
    const float cfe[4] = {cf.x, cf.y, cf.z, cf.w};
#pragma unroll
    for (int e = 0; e < 4; ++e) {
      aga[e] = fmaf(cfe[e], va[r][e + cx], aga[e]);
      agb[e] = fmaf(cfe[e], vb[r][e + cx], agb[e]);
    }
  }

  const float ctra[4] = {a1.x, a1.y, a1.z, a1.w};
  const float ctrb[4] = {b1.x, b1.y, b1.z, b1.w};
  const float rfa[4]  = {f0.x, f0.y, f0.z, f0.w};
  const float rfb[4]  = {f1.x, f1.y, f1.z, f1.w};
  float oae[4], obe[4];
#pragma unroll
  for (int e = 0; e < 4; ++e) {
    const float da = ctra[e] - rfa[e];
    const float db = ctrb[e] - rfb[e];
    oae[e] = aga[e] * __expf(-(da * da));
    obe[e] = agb[e] * __expf(-(db * db));
  }
  float4 oa, ob4;
  oa.x = oae[0]; oa.y = oae[1]; oa.z = oae[2]; oa.w = oae[3];
  ob4.x = obe[0]; ob4.y = obe[1]; ob4.z = obe[2]; ob4.w = obe[3];

  *(float4*)(o0 + y * W + x0) = oa;
  *(float4*)(o0 + HW + y * W + x0) = ob4;
}

// ---------------- fallback: R4 fused kernel (if ws too small) ----------------
__global__ __launch_bounds__(256) void fused_nbr_attn(const float* __restrict__ nbr,
                                                      const float* __restrict__ ref,
                                                      float* __restrict__ out) {
  const int tid  = threadIdx.x;
  const int lane = tid & 63;
  const int wv   = tid >> 6;
  const int px   = lane & 7;
  const int cg   = lane >> 3;

  const int pix = blockIdx.x * 32 + wv * 8 + px;
  const int b   = pix >> 16;
  const int p   = pix & (HW - 1);
  const int y   = p >> 8;
  const int x   = p & (W - 1);

  const int ym = (y == 0)     ? 1     : y - 1;
  const int yp = (y == H - 1) ? H - 2 : y + 1;
  const int xm = (x == 0)     ? 1     : x - 1;
  const int xp = (x == W - 1) ? W - 2 : x + 1;

  int off[9];
  off[0] = ym * W + xm; off[1] = ym * W + x; off[2] = ym * W + xp;
  off[3] = y  * W + xm; off[4] = y  * W + x; off[5] = y  * W + xp;
  off[6] = yp * W + xm; off[7] = yp * W + x; off[8] = yp * W + xp;
  const int ctr = y * W + x;

  const float* nb = nbr + ((size_t)b * C + cg * 8) * HW;
  const float* rb = ref + ((size_t)b * C + cg * 8) * HW;
  float*       ob = out + ((size_t)b * C + cg * 8) * HW;

  float v[8][9], r[8];
#pragma unroll
  for (int j = 0; j < 8; ++j) {
    r[j] = rb[j * HW + ctr];
#pragma unroll
    for (int k = 0; k < 9; ++k) v[j][k] = nb[j * HW + off[k]];
  }
  float sr = 0.f;
  float dot[9], ss[9];
#pragma unroll
  for (int k = 0; k < 9; ++k) { dot[k] = 0.f; ss[k] = 0.f; }
#pragma unroll
  for (int j = 0; j < 8; ++j) {
    sr = fmaf(r[j], r[j], sr);
#pragma unroll
    for (int k = 0; k < 9; ++k) {
      dot[k] = fmaf(r[j], v[j][k], dot[k]);
      ss[k]  = fmaf(v[j][k], v[j][k], ss[k]);
    }
  }
#pragma unroll
  for (int m = 8; m < 64; m <<= 1) {
    sr += __shfl_xor(sr, m);
#pragma unroll
    for (int k = 0; k < 9; ++k) {
      dot[k] += __shfl_xor(dot[k], m);
      ss[k]  += __shfl_xor(ss[k], m);
    }
  }
  const float invr = __frsqrt_rn(fmaxf(sr, 1e-24f));
  float d[9], invp[9];
  float mx = -INFINITY;
#pragma unroll
  for (int k = 0; k < 9; ++k) {
    invp[k] = __frsqrt_rn(fmaxf(ss[k], 1e-24f));
    d[k]    = dot[k] * invr * invp[k];
    mx      = fmaxf(mx, d[k]);
  }
  float s = 0.f;
  float coef[9];
#pragma unroll
  for (int k = 0; k < 9; ++k) {
    const float e = __expf(d[k] - mx);
    coef[k] = e;
    s += e;
  }
  const float sinv = 1.0f / s;
#pragma unroll
  for (int k = 0; k < 9; ++k) coef[k] *= sinv * invp[k];
#pragma unroll
  for (int j = 0; j < 8; ++j) {
    float a = 0.f;
#pragma unroll
    for (int k = 0; k < 9; ++k) a = fmaf(coef[k], v[j][k], a);
    const float diff = v[j][4] - r[j];
    const float wd   = __expf(-(diff * diff));
    ob[j * HW + ctr] = a * wd;
  }
}

extern "C" void kernel_launch(void* const* d_in, const int* in_sizes, int n_in,
                              void* d_out, int out_size, void* d_ws, size_t ws_size,
                              hipStream_t stream) {
  const float* nbr = (const float*)d_in[0];
  const float* ref = (const float*)d_in[1];
  float*       out = (float*)d_out;
  const size_t coef_bytes = (size_t)9 * PIX * sizeof(float);

  if (ws_size >= coef_bytes) {
    float* coef = (float*)d_ws;
    coef2_kernel<<<dim3(B * H), dim3(128), 0, stream>>>(nbr, ref, coef);   // 512 row-blocks
    apply_kernel<<<dim3(PIX / 4 * (C / 2) / 256), dim3(256), 0, stream>>>(nbr, ref, coef, out);
  } else {
    fused_nbr_attn<<<dim3(PIX / 32), dim3(256), 0, stream>>>(nbr, ref, out);
  }
}

// Round 10
// 46.329 us; speedup vs baseline: 2.0376x; 2.0376x over previous
//
#include <hip/hip_runtime.h>
#include <stdint.h>

// Two-kernel 3x3 neighborhood-attention.
//  K1 coef2_kernel: block = one image row (256 px), thread = 1 px. Channels
//    stream through double-buffered LDS (CHUNK=4 ch -> 32 KB total) via
//    global_load_lds. ~5 blocks/CU resident -> cross-block TLP hides the
//    per-chunk barrier drains (R7 at 64 KB had only 2 blocks/CU).
//    Each thread accumulates sr/dot[9]/ss[9] from LDS, softmax, coalesced
//    coef stores (patch l2norm folded in). No cross-lane reduction.
//  K2 apply_kernel: float4 streaming out = exp(-(nbr-ref)^2)*sum_k coef_k*nbr_k.
// Shapes: [b=2, c=64, h=256, w=256] fp32.

constexpr int C = 64, H = 256, W = 256, HW = H * W;
constexpr int B = 2, PIX = B * HW;
constexpr int CHUNK = 4;            // channels per staged chunk
constexpr int NCHUNK = C / CHUNK;   // 16

typedef const __attribute__((address_space(1))) void* gas_ptr;
typedef __attribute__((address_space(3))) void* las_ptr;

// ---------------- K1: coefficient kernel (LDS-staged) ----------------
__global__ __launch_bounds__(256) void coef2_kernel(const float* __restrict__ nbr,
                                                    const float* __restrict__ ref,
                                                    float* __restrict__ coef) {
  // buf[dbuf][ch][row: 0..2 = nbr @ {ym,y,yp}, 3 = ref @ y][W]  = 32 KB
  __shared__ float buf[2][CHUNK][4][W];

  const int tid  = threadIdx.x;
  const int lane = tid & 63;
  const int wv   = tid >> 6;          // wave 0..3

  const int by = blockIdx.x;          // b*256 + y
  const int b  = by >> 8;
  const int y  = by & 255;
  const int ym = (y == 0)     ? 1     : y - 1;   // jnp reflect
  const int yp = (y == H - 1) ? H - 2 : y + 1;

  const float* nbase = nbr + (size_t)b * C * HW;
  const float* rbase = ref + (size_t)b * C * HW;
  const int rowoff0 = ym * W, rowoff1 = y * W, rowoff2 = yp * W;

  // stage chunk -> buf[bi]: wave wv stages channel cc==wv (4 gll, 1KB each)
  auto stage = [&](int chunk, int bi) {
    const int cc = wv;
    const int c  = chunk * CHUNK + cc;
    const float* nrow = nbase + (size_t)c * HW;
    const float* rrow = rbase + (size_t)c * HW;
    __builtin_amdgcn_global_load_lds((gas_ptr)(nrow + rowoff0 + lane * 4),
                                     (las_ptr)&buf[bi][cc][0][0], 16, 0, 0);
    __builtin_amdgcn_global_load_lds((gas_ptr)(nrow + rowoff1 + lane * 4),
                                     (las_ptr)&buf[bi][cc][1][0], 16, 0, 0);
    __builtin_amdgcn_global_load_lds((gas_ptr)(nrow + rowoff2 + lane * 4),
                                     (las_ptr)&buf[bi][cc][2][0], 16, 0, 0);
    __builtin_amdgcn_global_load_lds((gas_ptr)(rrow + rowoff1 + lane * 4),
                                     (las_ptr)&buf[bi][cc][3][0], 16, 0, 0);
  };

  // thread <-> pixel mapping: x = tid (0..255)
  const int x  = tid;
  const int xm = (x == 0)     ? 1     : x - 1;
  const int xp = (x == W - 1) ? W - 2 : x + 1;

  float sr = 0.f;
  float dot[9], ss[9];
#pragma unroll
  for (int k = 0; k < 9; ++k) { dot[k] = 0.f; ss[k] = 0.f; }

  stage(0, 0);
  __syncthreads();   // drains vmcnt -> chunk 0 visible

#pragma unroll 2
  for (int i = 0; i < NCHUNK; ++i) {
    const int bi = i & 1;              // compile-time per unroll-2 copy
    if (i + 1 < NCHUNK) stage(i + 1, bi ^ 1);   // prefetch overlaps consume
#pragma unroll
    for (int cc = 0; cc < CHUNK; ++cc) {
      const float r  = buf[bi][cc][3][x];
      const float v0 = buf[bi][cc][0][xm], v1 = buf[bi][cc][0][x], v2 = buf[bi][cc][0][xp];
      const float v3 = buf[bi][cc][1][xm], v4 = buf[bi][cc][1][x], v5 = buf[bi][cc][1][xp];
      const float v6 = buf[bi][cc][2][xm], v7 = buf[bi][cc][2][x], v8 = buf[bi][cc][2][xp];
      sr = fmaf(r, r, sr);
      dot[0] = fmaf(r, v0, dot[0]); ss[0] = fmaf(v0, v0, ss[0]);
      dot[1] = fmaf(r, v1, dot[1]); ss[1] = fmaf(v1, v1, ss[1]);
      dot[2] = fmaf(r, v2, dot[2]); ss[2] = fmaf(v2, v2, ss[2]);
      dot[3] = fmaf(r, v3, dot[3]); ss[3] = fmaf(v3, v3, ss[3]);
      dot[4] = fmaf(r, v4, dot[4]); ss[4] = fmaf(v4, v4, ss[4]);
      dot[5] = fmaf(r, v5, dot[5]); ss[5] = fmaf(v5, v5, ss[5]);
      dot[6] = fmaf(r, v6, dot[6]); ss[6] = fmaf(v6, v6, ss[6]);
      dot[7] = fmaf(r, v7, dot[7]); ss[7] = fmaf(v7, v7, ss[7]);
      dot[8] = fmaf(r, v8, dot[8]); ss[8] = fmaf(v8, v8, ss[8]);
    }
    __syncthreads();   // next chunk ready + protects dbuf reuse
  }

  // ---- normalize + softmax over the 9 neighbors ----
  const float invr = __frsqrt_rn(fmaxf(sr, 1e-24f));
  float d[9], invp[9];
  float mx = -INFINITY;
#pragma unroll
  for (int k = 0; k < 9; ++k) {
    invp[k] = __frsqrt_rn(fmaxf(ss[k], 1e-24f));
    d[k]    = dot[k] * invr * invp[k];
    mx      = fmaxf(mx, d[k]);
  }
  float s = 0.f;
  float cf[9];
#pragma unroll
  for (int k = 0; k < 9; ++k) {
    cf[k] = __expf(d[k] - mx);
    s += cf[k];
  }
  const float sinv = 1.0f / s;

  const int pix = by * W + x;         // b*HW + y*W + x
#pragma unroll
  for (int k = 0; k < 9; ++k)
    coef[(size_t)k * PIX + pix] = cf[k] * sinv * invp[k];   // patch l2norm folded
}

// ---------------- K2: apply kernel (proven; unchanged) ----------------
__global__ __launch_bounds__(256) void apply_kernel(const float* __restrict__ nbr,
                                                    const float* __restrict__ ref,
                                                    const float* __restrict__ coef,
                                                    float* __restrict__ out) {
  const int gid  = blockIdx.x * 256 + threadIdx.x;
  const int lane = gid & 63;
  const int x0   = lane * 4;
  const int t    = gid >> 6;
  const int y    = t & 255;
  const int u    = t >> 8;
  const int b    = u >> 5;
  const int c0   = (u & 31) * 2;

  const int ym = (y == 0)     ? 1     : y - 1;
  const int yp = (y == H - 1) ? H - 2 : y + 1;

  const float* n0  = nbr + ((size_t)b * C + c0) * HW;
  const float* n1  = n0 + HW;
  const float* r0p = ref + ((size_t)b * C + c0) * HW;
  float*       o0  = out + ((size_t)b * C + c0) * HW;

  const float4 a0 = *(const float4*)(n0 + ym * W + x0);
  const float4 a1 = *(const float4*)(n0 + y  * W + x0);
  const float4 a2 = *(const float4*)(n0 + yp * W + x0);
  const float4 b0 = *(const float4*)(n1 + ym * W + x0);
  const float4 b1 = *(const float4*)(n1 + y  * W + x0);
  const float4 b2 = *(const float4*)(n1 + yp * W + x0);
  const float4 f0 = *(const float4*)(r0p + y * W + x0);
  const float4 f1 = *(const float4*)(r0p + HW + y * W + x0);

  float La0 = __shfl(a0.w, lane - 1), Ra0 = __shfl(a0.x, lane + 1);
  float La1 = __shfl(a1.w, lane - 1), Ra1 = __shfl(a1.x, lane + 1);
  float La2 = __shfl(a2.w, lane - 1), Ra2 = __shfl(a2.x, lane + 1);
  float Lb0 = __shfl(b0.w, lane - 1), Rb0 = __shfl(b0.x, lane + 1);
  float Lb1 = __shfl(b1.w, lane - 1), Rb1 = __shfl(b1.x, lane + 1);
  float Lb2 = __shfl(b2.w, lane - 1), Rb2 = __shfl(b2.x, lane + 1);
  if (lane == 0)  { La0 = a0.y; La1 = a1.y; La2 = a2.y; Lb0 = b0.y; Lb1 = b1.y; Lb2 = b2.y; }
  if (lane == 63) { Ra0 = a0.z; Ra1 = a1.z; Ra2 = a2.z; Rb0 = b0.z; Rb1 = b1.z; Rb2 = b2.z; }

  float va[3][6] = {{La0, a0.x, a0.y, a0.z, a0.w, Ra0},
                    {La1, a1.x, a1.y, a1.z, a1.w, Ra1},
                    {La2, a2.x, a2.y, a2.z, a2.w, Ra2}};
  float vb[3][6] = {{Lb0, b0.x, b0.y, b0.z, b0.w, Rb0},
                    {Lb1, b1.x, b1.y, b1.z, b1.w, Rb1},
                    {Lb2, b2.x, b2.y, b2.z, b2.w, Rb2}};

  const int cbase = b * HW + y * W + x0;
  float aga[4] = {0.f, 0.f, 0.f, 0.f};
  float agb[4] = {0.f, 0.f, 0.f, 0.f};
#pragma unroll
  for (int k = 0; k < 9; ++k) {
    const float4 cf = *(const float4*)(coef + (size_t)k * PIX + cbase);
    const int r  = k / 3;
    const int cx = k % 3;
    const float cfe[4] = {cf.x, cf.y, cf.z, cf.w};
#pragma unroll
    for (int e = 0; e < 4; ++e) {
      aga[e] = fmaf(cfe[e], va[r][e + cx], aga[e]);
      agb[e] = fmaf(cfe[e], vb[r][e + cx], agb[e]);
    }
  }

  const float ctra[4] = {a1.x, a1.y, a1.z, a1.w};
  const float ctrb[4] = {b1.x, b1.y, b1.z, b1.w};
  const float rfa[4]  = {f0.x, f0.y, f0.z, f0.w};
  const float rfb[4]  = {f1.x, f1.y, f1.z, f1.w};
  float oae[4], obe[4];
#pragma unroll
  for (int e = 0; e < 4; ++e) {
    const float da = ctra[e] - rfa[e];
    const float db = ctrb[e] - rfb[e];
    oae[e] = aga[e] * __expf(-(da * da));
    obe[e] = agb[e] * __expf(-(db * db));
  }
  float4 oa, ob4;
  oa.x = oae[0]; oa.y = oae[1]; oa.z = oae[2]; oa.w = oae[3];
  ob4.x = obe[0]; ob4.y = obe[1]; ob4.z = obe[2]; ob4.w = obe[3];

  *(float4*)(o0 + y * W + x0) = oa;
  *(float4*)(o0 + HW + y * W + x0) = ob4;
}

// ---------------- fallback: R4 fused kernel (if ws too small) ----------------
__global__ __launch_bounds__(256) void fused_nbr_attn(const float* __restrict__ nbr,
                                                      const float* __restrict__ ref,
                                                      float* __restrict__ out) {
  const int tid  = threadIdx.x;
  const int lane = tid & 63;
  const int wv   = tid >> 6;
  const int px   = lane & 7;
  const int cg   = lane >> 3;

  const int pix = blockIdx.x * 32 + wv * 8 + px;
  const int b   = pix >> 16;
  const int p   = pix & (HW - 1);
  const int y   = p >> 8;
  const int x   = p & (W - 1);

  const int ym = (y == 0)     ? 1     : y - 1;
  const int yp = (y == H - 1) ? H - 2 : y + 1;
  const int xm = (x == 0)     ? 1     : x - 1;
  const int xp = (x == W - 1) ? W - 2 : x + 1;

  int off[9];
  off[0] = ym * W + xm; off[1] = ym * W + x; off[2] = ym * W + xp;
  off[3] = y  * W + xm; off[4] = y  * W + x; off[5] = y  * W + xp;
  off[6] = yp * W + xm; off[7] = yp * W + x; off[8] = yp * W + xp;
  const int ctr = y * W + x;

  const float* nb = nbr + ((size_t)b * C + cg * 8) * HW;
  const float* rb = ref + ((size_t)b * C + cg * 8) * HW;
  float*       ob = out + ((size_t)b * C + cg * 8) * HW;

  float v[8][9], r[8];
#pragma unroll
  for (int j = 0; j < 8; ++j) {
    r[j] = rb[j * HW + ctr];
#pragma unroll
    for (int k = 0; k < 9; ++k) v[j][k] = nb[j * HW + off[k]];
  }
  float sr = 0.f;
  float dot[9], ss[9];
#pragma unroll
  for (int k = 0; k < 9; ++k) { dot[k] = 0.f; ss[k] = 0.f; }
#pragma unroll
  for (int j = 0; j < 8; ++j) {
    sr = fmaf(r[j], r[j], sr);
#pragma unroll
    for (int k = 0; k < 9; ++k) {
      dot[k] = fmaf(r[j], v[j][k], dot[k]);
      ss[k]  = fmaf(v[j][k], v[j][k], ss[k]);
    }
  }
#pragma unroll
  for (int m = 8; m < 64; m <<= 1) {
    sr += __shfl_xor(sr, m);
#pragma unroll
    for (int k = 0; k < 9; ++k) {
      dot[k] += __shfl_xor(dot[k], m);
      ss[k]  += __shfl_xor(ss[k], m);
    }
  }
  const float invr = __frsqrt_rn(fmaxf(sr, 1e-24f));
  float d[9], invp[9];
  float mx = -INFINITY;
#pragma unroll
  for (int k = 0; k < 9; ++k) {
    invp[k] = __frsqrt_rn(fmaxf(ss[k], 1e-24f));
    d[k]    = dot[k] * invr * invp[k];
    mx      = fmaxf(mx, d[k]);
  }
  float s = 0.f;
  float coef[9];
#pragma unroll
  for (int k = 0; k < 9; ++k) {
    const float e = __expf(d[k] - mx);
    coef[k] = e;
    s += e;
  }
  const float sinv = 1.0f / s;
#pragma unroll
  for (int k = 0; k < 9; ++k) coef[k] *= sinv * invp[k];
#pragma unroll
  for (int j = 0; j < 8; ++j) {
    float a = 0.f;
#pragma unroll
    for (int k = 0; k < 9; ++k) a = fmaf(coef[k], v[j][k], a);
    const float diff = v[j][4] - r[j];
    const float wd   = __expf(-(diff * diff));
    ob[j * HW + ctr] = a * wd;
  }
}

extern "C" void kernel_launch(void* const* d_in, const int* in_sizes, int n_in,
                              void* d_out, int out_size, void* d_ws, size_t ws_size,
                              hipStream_t stream) {
  const float* nbr = (const float*)d_in[0];
  const float* ref = (const float*)d_in[1];
  float*       out = (float*)d_out;
  const size_t coef_bytes = (size_t)9 * PIX * sizeof(float);

  if (ws_size >= coef_bytes) {
    float* coef = (float*)d_ws;
    coef2_kernel<<<dim3(B * H), dim3(256), 0, stream>>>(nbr, ref, coef);   // 512 row-blocks
    apply_kernel<<<dim3(PIX / 4 * (C / 2) / 256), dim3(256), 0, stream>>>(nbr, ref, coef, out);
  } else {
    fused_nbr_attn<<<dim3(PIX / 32), dim3(256), 0, stream>>>(nbr, ref, out);
  }
}

// Round 12
// 42.690 us; speedup vs baseline: 2.2112x; 1.0852x over previous
//
#include <hip/hip_runtime.h>
#include <stdint.h>

// Two-kernel 3x3 neighborhood-attention.
//  K1 coef2_kernel: block = one image row (256 px), thread = 1 px. Channels
//    stream through double-buffered LDS (CHUNK=4 -> 32 KB) via global_load_lds.
//    XCD-aware blockIdx swizzle: each XCD gets a contiguous 64-row band, so
//    the 3x y-duplicated nbr staging L2-hits (band chunk working set ~520 KB
//    << 4 MB XCD L2). Thread-local sr/dot[9]/ss[9], softmax, coalesced stores.
//  K2 apply_kernel: float4 streaming out = exp(-(nbr-ref)^2)*sum_k coef_k*nbr_k,
//    same chunked XCD swizzle (grid=4096 -> chunk 512, bijective!).
// Shapes: [b=2, c=64, h=256, w=256] fp32.

constexpr int C = 64, H = 256, W = 256, HW = H * W;
constexpr int B = 2, PIX = B * HW;
constexpr int CHUNK = 4;            // channels per staged chunk
constexpr int NCHUNK = C / CHUNK;   // 16

typedef const __attribute__((address_space(1))) void* gas_ptr;
typedef __attribute__((address_space(3))) void* las_ptr;

// ---------------- K1: coefficient kernel (LDS-staged) ----------------
__global__ __launch_bounds__(256) void coef2_kernel(const float* __restrict__ nbr,
                                                    const float* __restrict__ ref,
                                                    float* __restrict__ coef) {
  // buf[dbuf][ch][row: 0..2 = nbr @ {ym,y,yp}, 3 = ref @ y][W]  = 32 KB
  __shared__ float buf[2][CHUNK][4][W];

  const int tid  = threadIdx.x;
  const int lane = tid & 63;
  const int wv   = tid >> 6;          // wave 0..3

  // XCD-aware swizzle: 512 blocks, 8 XCDs -> XCD k owns rows [k*64,(k+1)*64)
  const int by = ((blockIdx.x & 7) << 6) | (blockIdx.x >> 3);   // bijective on [0,512)
  const int b  = by >> 8;
  const int y  = by & 255;
  const int ym = (y == 0)     ? 1     : y - 1;   // jnp reflect
  const int yp = (y == H - 1) ? H - 2 : y + 1;

  const float* nbase = nbr + (size_t)b * C * HW;
  const float* rbase = ref + (size_t)b * C * HW;
  const int rowoff0 = ym * W, rowoff1 = y * W, rowoff2 = yp * W;

  // stage chunk -> buf[bi]: wave wv stages channel cc==wv (4 gll, 1KB each)
  auto stage = [&](int chunk, int bi) {
    const int cc = wv;
    const int c  = chunk * CHUNK + cc;
    const float* nrow = nbase + (size_t)c * HW;
    const float* rrow = rbase + (size_t)c * HW;
    __builtin_amdgcn_global_load_lds((gas_ptr)(nrow + rowoff0 + lane * 4),
                                     (las_ptr)&buf[bi][cc][0][0], 16, 0, 0);
    __builtin_amdgcn_global_load_lds((gas_ptr)(nrow + rowoff1 + lane * 4),
                                     (las_ptr)&buf[bi][cc][1][0], 16, 0, 0);
    __builtin_amdgcn_global_load_lds((gas_ptr)(nrow + rowoff2 + lane * 4),
                                     (las_ptr)&buf[bi][cc][2][0], 16, 0, 0);
    __builtin_amdgcn_global_load_lds((gas_ptr)(rrow + rowoff1 + lane * 4),
                                     (las_ptr)&buf[bi][cc][3][0], 16, 0, 0);
  };

  // thread <-> pixel mapping: x = tid (0..255)
  const int x  = tid;
  const int xm = (x == 0)     ? 1     : x - 1;
  const int xp = (x == W - 1) ? W - 2 : x + 1;

  float sr = 0.f;
  float dot[9], ss[9];
#pragma unroll
  for (int k = 0; k < 9; ++k) { dot[k] = 0.f; ss[k] = 0.f; }

  stage(0, 0);
  __syncthreads();   // drains vmcnt -> chunk 0 visible

#pragma unroll 2
  for (int i = 0; i < NCHUNK; ++i) {
    const int bi = i & 1;              // compile-time per unroll-2 copy
    if (i + 1 < NCHUNK) stage(i + 1, bi ^ 1);   // prefetch overlaps consume
#pragma unroll
    for (int cc = 0; cc < CHUNK; ++cc) {
      const float r  = buf[bi][cc][3][x];
      const float v0 = buf[bi][cc][0][xm], v1 = buf[bi][cc][0][x], v2 = buf[bi][cc][0][xp];
      const float v3 = buf[bi][cc][1][xm], v4 = buf[bi][cc][1][x], v5 = buf[bi][cc][1][xp];
      const float v6 = buf[bi][cc][2][xm], v7 = buf[bi][cc][2][x], v8 = buf[bi][cc][2][xp];
      sr = fmaf(r, r, sr);
      dot[0] = fmaf(r, v0, dot[0]); ss[0] = fmaf(v0, v0, ss[0]);
      dot[1] = fmaf(r, v1, dot[1]); ss[1] = fmaf(v1, v1, ss[1]);
      dot[2] = fmaf(r, v2, dot[2]); ss[2] = fmaf(v2, v2, ss[2]);
      dot[3] = fmaf(r, v3, dot[3]); ss[3] = fmaf(v3, v3, ss[3]);
      dot[4] = fmaf(r, v4, dot[4]); ss[4] = fmaf(v4, v4, ss[4]);
      dot[5] = fmaf(r, v5, dot[5]); ss[5] = fmaf(v5, v5, ss[5]);
      dot[6] = fmaf(r, v6, dot[6]); ss[6] = fmaf(v6, v6, ss[6]);
      dot[7] = fmaf(r, v7, dot[7]); ss[7] = fmaf(v7, v7, ss[7]);
      dot[8] = fmaf(r, v8, dot[8]); ss[8] = fmaf(v8, v8, ss[8]);
    }
    __syncthreads();   // next chunk ready + protects dbuf reuse
  }

  // ---- normalize + softmax over the 9 neighbors ----
  const float invr = __frsqrt_rn(fmaxf(sr, 1e-24f));
  float d[9], invp[9];
  float mx = -INFINITY;
#pragma unroll
  for (int k = 0; k < 9; ++k) {
    invp[k] = __frsqrt_rn(fmaxf(ss[k], 1e-24f));
    d[k]    = dot[k] * invr * invp[k];
    mx      = fmaxf(mx, d[k]);
  }
  float s = 0.f;
  float cf[9];
#pragma unroll
  for (int k = 0; k < 9; ++k) {
    cf[k] = __expf(d[k] - mx);
    s += cf[k];
  }
  const float sinv = 1.0f / s;

  const int pix = by * W + x;         // b*HW + y*W + x
#pragma unroll
  for (int k = 0; k < 9; ++k)
    coef[(size_t)k * PIX + pix] = cf[k] * sinv * invp[k];   // patch l2norm folded
}

// ---------------- K2: apply kernel (proven; + XCD swizzle, grid=4096) ----------------
__global__ __launch_bounds__(256) void apply_kernel(const float* __restrict__ nbr,
                                                    const float* __restrict__ ref,
                                                    const float* __restrict__ coef,
                                                    float* __restrict__ out) {
  // 4096 blocks, 8 XCDs -> XCD k owns a contiguous 512-block chunk
  const int blk  = ((blockIdx.x & 7) << 9) | (blockIdx.x >> 3);  // bijective on [0,4096)
  const int gid  = blk * 256 + threadIdx.x;
  const int lane = gid & 63;
  const int x0   = lane * 4;
  const int t    = gid >> 6;
  const int y    = t & 255;
  const int u    = t >> 8;
  const int b    = u >> 5;
  const int c0   = (u & 31) * 2;

  const int ym = (y == 0)     ? 1     : y - 1;
  const int yp = (y == H - 1) ? H - 2 : y + 1;

  const float* n0  = nbr + ((size_t)b * C + c0) * HW;
  const float* n1  = n0 + HW;
  const float* r0p = ref + ((size_t)b * C + c0) * HW;
  float*       o0  = out + ((size_t)b * C + c0) * HW;

  const float4 a0 = *(const float4*)(n0 + ym * W + x0);
  const float4 a1 = *(const float4*)(n0 + y  * W + x0);
  const float4 a2 = *(const float4*)(n0 + yp * W + x0);
  const float4 b0 = *(const float4*)(n1 + ym * W + x0);
  const float4 b1 = *(const float4*)(n1 + y  * W + x0);
  const float4 b2 = *(const float4*)(n1 + yp * W + x0);
  const float4 f0 = *(const float4*)(r0p + y * W + x0);
  const float4 f1 = *(const float4*)(r0p + HW + y * W + x0);

  float La0 = __shfl(a0.w, lane - 1), Ra0 = __shfl(a0.x, lane + 1);
  float La1 = __shfl(a1.w, lane - 1), Ra1 = __shfl(a1.x, lane + 1);
  float La2 = __shfl(a2.w, lane - 1), Ra2 = __shfl(a2.x, lane + 1);
  float Lb0 = __shfl(b0.w, lane - 1), Rb0 = __shfl(b0.x, lane + 1);
  float Lb1 = __shfl(b1.w, lane - 1), Rb1 = __shfl(b1.x, lane + 1);
  float Lb2 = __shfl(b2.w, lane - 1), Rb2 = __shfl(b2.x, lane + 1);
  if (lane == 0)  { La0 = a0.y; La1 = a1.y; La2 = a2.y; Lb0 = b0.y; Lb1 = b1.y; Lb2 = b2.y; }
  if (lane == 63) { Ra0 = a0.z; Ra1 = a1.z; Ra2 = a2.z; Rb0 = b0.z; Rb1 = b1.z; Rb2 = b2.z; }

  float va[3][6] = {{La0, a0.x, a0.y, a0.z, a0.w, Ra0},
                    {La1, a1.x, a1.y, a1.z, a1.w, Ra1},
                    {La2, a2.x, a2.y, a2.z, a2.w, Ra2}};
  float vb[3][6] = {{Lb0, b0.x, b0.y, b0.z, b0.w, Rb0},
                    {Lb1, b1.x, b1.y, b1.z, b1.w, Rb1},
                    {Lb2, b2.x, b2.y, b2.z, b2.w, Rb2}};

  const int cbase = b * HW + y * W + x0;
  float aga[4] = {0.f, 0.f, 0.f, 0.f};
  float agb[4] = {0.f, 0.f, 0.f, 0.f};
#pragma unroll
  for (int k = 0; k < 9; ++k) {
    const float4 cf = *(const float4*)(coef + (size_t)k * PIX + cbase);
    const int r  = k / 3;
    const int cx = k % 3;
    const float cfe[4] = {cf.x, cf.y, cf.z, cf.w};
#pragma unroll
    for (int e = 0; e < 4; ++e) {
      aga[e] = fmaf(cfe[e], va[r][e + cx], aga[e]);
      agb[e] = fmaf(cfe[e], vb[r][e + cx], agb[e]);
    }
  }

  const float ctra[4] = {a1.x, a1.y, a1.z, a1.w};
  const float ctrb[4] = {b1.x, b1.y, b1.z, b1.w};
  const float rfa[4]  = {f0.x, f0.y, f0.z, f0.w};
  const float rfb[4]  = {f1.x, f1.y, f1.z, f1.w};
  float oae[4], obe[4];
#pragma unroll
  for (int e = 0; e < 4; ++e) {
    const float da = ctra[e] - rfa[e];
    const float db = ctrb[e] - rfb[e];
    oae[e] = aga[e] * __expf(-(da * da));
    obe[e] = agb[e] * __expf(-(db * db));
  }
  float4 oa, ob4;
  oa.x = oae[0]; oa.y = oae[1]; oa.z = oae[2]; oa.w = oae[3];
  ob4.x = obe[0]; ob4.y = obe[1]; ob4.z = obe[2]; ob4.w = obe[3];

  *(float4*)(o0 + y * W + x0) = oa;
  *(float4*)(o0 + HW + y * W + x0) = ob4;
}

// ---------------- fallback: R4 fused kernel (if ws too small) ----------------
__global__ __launch_bounds__(256) void fused_nbr_attn(const float* __restrict__ nbr,
                                                      const float* __restrict__ ref,
                                                      float* __restrict__ out) {
  const int tid  = threadIdx.x;
  const int lane = tid & 63;
  const int wv   = tid >> 6;
  const int px   = lane & 7;
  const int cg   = lane >> 3;

  const int pix = blockIdx.x * 32 + wv * 8 + px;
  const int b   = pix >> 16;
  const int p   = pix & (HW - 1);
  const int y   = p >> 8;
  const int x   = p & (W - 1);

  const int ym = (y == 0)     ? 1     : y - 1;
  const int yp = (y == H - 1) ? H - 2 : y + 1;
  const int xm = (x == 0)     ? 1     : x - 1;
  const int xp = (x == W - 1) ? W - 2 : x + 1;

  int off[9];
  off[0] = ym * W + xm; off[1] = ym * W + x; off[2] = ym * W + xp;
  off[3] = y  * W + xm; off[4] = y  * W + x; off[5] = y  * W + xp;
  off[6] = yp * W + xm; off[7] = yp * W + x; off[8] = yp * W + xp;
  const int ctr = y * W + x;

  const float* nb = nbr + ((size_t)b * C + cg * 8) * HW;
  const float* rb = ref + ((size_t)b * C + cg * 8) * HW;
  float*       ob = out + ((size_t)b * C + cg * 8) * HW;

  float v[8][9], r[8];
#pragma unroll
  for (int j = 0; j < 8; ++j) {
    r[j] = rb[j * HW + ctr];
#pragma unroll
    for (int k = 0; k < 9; ++k) v[j][k] = nb[j * HW + off[k]];
  }
  float sr = 0.f;
  float dot[9], ss[9];
#pragma unroll
  for (int k = 0; k < 9; ++k) { dot[k] = 0.f; ss[k] = 0.f; }
#pragma unroll
  for (int j = 0; j < 8; ++j) {
    sr = fmaf(r[j], r[j], sr);
#pragma unroll
    for (int k = 0; k < 9; ++k) {
      dot[k] = fmaf(r[j], v[j][k], dot[k]);
      ss[k]  = fmaf(v[j][k], v[j][k], ss[k]);
    }
  }
#pragma unroll
  for (int m = 8; m < 64; m <<= 1) {
    sr += __shfl_xor(sr, m);
#pragma unroll
    for (int k = 0; k < 9; ++k) {
      dot[k] += __shfl_xor(dot[k], m);
      ss[k]  += __shfl_xor(ss[k], m);
    }
  }
  const float invr = __frsqrt_rn(fmaxf(sr, 1e-24f));
  float d[9], invp[9];
  float mx = -INFINITY;
#pragma unroll
  for (int k = 0; k < 9; ++k) {
    invp[k] = __frsqrt_rn(fmaxf(ss[k], 1e-24f));
    d[k]    = dot[k] * invr * invp[k];
    mx      = fmaxf(mx, d[k]);
  }
  float s = 0.f;
  float coef[9];
#pragma unroll
  for (int k = 0; k < 9; ++k) {
    const float e = __expf(d[k] - mx);
    coef[k] = e;
    s += e;
  }
  const float sinv = 1.0f / s;
#pragma unroll
  for (int k = 0; k < 9; ++k) coef[k] *= sinv * invp[k];
#pragma unroll
  for (int j = 0; j < 8; ++j) {
    float a = 0.f;
#pragma unroll
    for (int k = 0; k < 9; ++k) a = fmaf(coef[k], v[j][k], a);
    const float diff = v[j][4] - r[j];
    const float wd   = __expf(-(diff * diff));
    ob[j * HW + ctr] = a * wd;
  }
}

extern "C" void kernel_launch(void* const* d_in, const int* in_sizes, int n_in,
                              void* d_out, int out_size, void* d_ws, size_t ws_size,
                              hipStream_t stream) {
  const float* nbr = (const float*)d_in[0];
  const float* ref = (const float*)d_in[1];
  float*       out = (float*)d_out;
  const size_t coef_bytes = (size_t)9 * PIX * sizeof(float);

  if (ws_size >= coef_bytes) {
    float* coef = (float*)d_ws;
    coef2_kernel<<<dim3(B * H), dim3(256), 0, stream>>>(nbr, ref, coef);     // 512 row-blocks
    apply_kernel<<<dim3(PIX / 4 * (C / 2) / 256), dim3(256), 0, stream>>>(nbr, ref, coef, out);  // 4096
  } else {
    fused_nbr_attn<<<dim3(PIX / 32), dim3(256), 0, stream>>>(nbr, ref, out);
  }
}